// Round 6
// baseline (291.061 us; speedup 1.0000x reference)
//
#include <hip/hip_runtime.h>
#include <math.h>

#define NTOK 4096
#define DDIM 1024
#define HDIM 4096
#define NEXP 8
#define BK 64
#define T0MAX 40   // >= NTOK/128 + NEXP-1 live tiles for GEMM0
#define T1MAX 72   // >= NTOK/64  + NEXP-1 live tiles for GEMM1

typedef float f32x4 __attribute__((ext_vector_type(4)));
typedef __bf16 bf16x8 __attribute__((ext_vector_type(8)));
typedef const __attribute__((address_space(1))) void gas_t;
typedef __attribute__((address_space(3))) void las_t;

__device__ __forceinline__ unsigned short f2bf(float f) {
    union { float f; unsigned u; } v; v.f = f;
    unsigned u = v.u;
    return (unsigned short)((u + 0x7fffu + ((u >> 16) & 1u)) >> 16);
}

__device__ __forceinline__ float gelu_f(float v) {
    return 0.5f * v * (1.0f + erff(v * 0.70710678118654752f));
}

// ---------------- gating: one wave per token (also emits xb = bf16(x)) ----------------
__global__ void k_gate(const float* __restrict__ x, const float* __restrict__ gw,
                       const float* __restrict__ gb, unsigned short* __restrict__ xb,
                       int* __restrict__ sel, int* __restrict__ counts) {
    const int wid = threadIdx.x >> 6, lane = threadIdx.x & 63;
    const int tok = blockIdx.x * 4 + wid;
    const float* xr = x + (long)tok * DDIM;
    unsigned short* xbr = xb + (long)tok * DDIM;
    float s[NEXP];
#pragma unroll
    for (int e = 0; e < NEXP; ++e) s[e] = 0.f;
    for (int it = 0; it < DDIM / 64; ++it) {
        const int kk = it * 64 + lane;
        const float xv = xr[kk];
        xbr[kk] = f2bf(xv);
        const float4* g4 = (const float4*)(gw + (long)kk * NEXP);
        const float4 g0 = g4[0], g1 = g4[1];
        s[0] += xv * g0.x; s[1] += xv * g0.y; s[2] += xv * g0.z; s[3] += xv * g0.w;
        s[4] += xv * g1.x; s[5] += xv * g1.y; s[6] += xv * g1.z; s[7] += xv * g1.w;
    }
#pragma unroll
    for (int e = 0; e < NEXP; ++e)
        for (int off = 32; off > 0; off >>= 1)
            s[e] += __shfl_down(s[e], off);
    if (lane == 0) {
        float best = s[0] + gb[0]; int bi = 0;
#pragma unroll
        for (int e = 1; e < NEXP; ++e) {
            const float v = s[e] + gb[e];
            if (v > best) { best = v; bi = e; }   // strict > keeps lowest index (np.argmax)
        }
        sel[tok] = bi;
        atomicAdd(&counts[bi], 1);
    }
}

// ---------------- fill token lists + scan + live-tile tables ----------------
__global__ void k_fill(const int* __restrict__ sel, const int* __restrict__ counts,
                       int* __restrict__ cur, int* __restrict__ offs,
                       int* __restrict__ list, int* __restrict__ t0,
                       int* __restrict__ t1, float* __restrict__ laux) {
    const int t = blockIdx.x * blockDim.x + threadIdx.x;
    if (t < NTOK) {
        const int e = sel[t];
        int off_e = 0;
#pragma unroll
        for (int j = 0; j < NEXP; ++j) off_e += (j < e) ? counts[j] : 0;  // no array (rule #20)
        list[off_e + atomicAdd(&cur[e], 1)] = t;
    }
    if (t == 0) {
        int o = 0;
        for (int e = 0; e < NEXP; ++e) { offs[e] = o; o += counts[e]; }
        offs[NEXP] = o;
        int i0 = 0;
        for (int e = 0; e < NEXP; ++e)
            for (int m = 0; m < counts[e]; m += 128) t0[i0++] = (e << 16) | m;
        while (i0 < T0MAX) t0[i0++] = -1;
        int i1 = 0;
        for (int e = 0; e < NEXP; ++e)
            for (int m = 0; m < counts[e]; m += 64) t1[i1++] = (e << 16) | m;
        while (i1 < T1MAX) t1[i1++] = -1;
        laux[0] = 0.f;
    }
}

// ---------------- W [e][K][NC] f32 -> Wt [e][NC][K] bf16 (transpose-convert) ----------------
template<int K, int NC>
__global__ __launch_bounds__(256) void k_cvt_w(const float* __restrict__ W,
                                               unsigned short* __restrict__ Wt) {
    __shared__ unsigned short T[64 * 68];   // [n][k], stride 68 breaks bank conflicts
    const int ktiles = K / 64;
    const int e  = blockIdx.y / ktiles;
    const int k0 = (blockIdx.y % ktiles) * 64;
    const int n0 = blockIdx.x * 64;
    const float* src = W + (long)e * K * NC + (long)k0 * NC + n0;
    const int tid = threadIdx.x;
#pragma unroll
    for (int i = 0; i < 4; ++i) {
        const int idx = tid + i * 256;
        const int k = idx >> 4, c4 = (idx & 15) * 4;
        const float4 v = *(const float4*)(src + (long)k * NC + c4);
        T[(c4 + 0) * 68 + k] = f2bf(v.x);
        T[(c4 + 1) * 68 + k] = f2bf(v.y);
        T[(c4 + 2) * 68 + k] = f2bf(v.z);
        T[(c4 + 3) * 68 + k] = f2bf(v.w);
    }
    __syncthreads();
    unsigned short* dst = Wt + (long)e * NC * K + (long)n0 * K + k0;
#pragma unroll
    for (int i = 0; i < 2; ++i) {
        const int idx = tid + i * 256;
        const int n = idx >> 3, c8 = (idx & 7) * 8;
        *(ushort4*)(dst + (long)n * K + c8)     = *(const ushort4*)&T[n * 68 + c8];
        *(ushort4*)(dst + (long)n * K + c8 + 4) = *(const ushort4*)&T[n * 68 + c8 + 4];
    }
}

// ---------------- grouped GEMM: m97 structure + compact live-tile grid ----------------
// 256 thr = 4 waves, per-wave (BM/2)x(BN/2). Single-buffered LDS, XOR swizzle via
// pre-swizzled global source, global_load_lds w=16, compact ttab grid (~95% live).
// MODE 0: BM=128,BN=128; epilogue = two 64-row LDS re-tile passes (stride-136 shorts)
//         -> 16B coalesced bf16 stores; LDS stays exactly 32KB -> 5 blocks/CU.
// MODE 1: BM=64,BN=64 (grid 16x72=1152 blocks, fixes grid starvation); direct f32 stores.
template<int MODE, int BM_, int BN_>
__global__ __launch_bounds__(256) void k_gemm(
        const unsigned short* __restrict__ Ain,
        const unsigned short* __restrict__ Wt,
        const float* __restrict__ bias,
        unsigned short* __restrict__ Hout, float* __restrict__ Yout,
        const int* __restrict__ counts, const int* __restrict__ offs,
        const int* __restrict__ list, const int* __restrict__ ttab) {
    static_assert(BM_ % 32 == 0 && BN_ % 32 == 0, "tile");
    constexpr int K  = (MODE == 0) ? DDIM : HDIM;
    constexpr int NC = (MODE == 0) ? HDIM : DDIM;
    constexpr int NT = K / BK;
    constexpr int FM = BM_ / 32;
    constexpr int FN = BN_ / 32;
    constexpr int LA = BM_ / 32;   // A loads per thread per tile
    constexpr int LB = BN_ / 32;
    constexpr int EP = 136;        // epilogue re-tile stride (shorts), 16B-mult

    const int code = ttab[blockIdx.y];
    if (code < 0) return;
    const int e  = code >> 16;
    const int m0 = code & 0xFFFF;
    const int cnt  = counts[e];
    const int base = offs[e];
    const int n0   = blockIdx.x * BN_;

    __shared__ __align__(16) unsigned short sh[BM_ * 64 + BN_ * 64];
    unsigned short* Asb = sh;
    unsigned short* Btb = sh + BM_ * 64;

    const int tid  = threadIdx.x;
    const int lane = tid & 63, wid = tid >> 6;
    const int lr = lane >> 3, lc = lane & 7;
    const int sb = (lc * 16) ^ (lr << 4);        // pre-swizzled source byte offset

    const unsigned short* pA[LA];
#pragma unroll
    for (int i = 0; i < LA; ++i) {
        const int r = wid * (BM_ / 4) + i * 8 + lr;
        int rr = m0 + r; if (rr >= cnt) rr = cnt - 1;
        const long grow = (MODE == 0) ? (long)list[base + rr] : (long)(base + rr);
        pA[i] = (const unsigned short*)((const char*)(Ain + grow * K) + sb);
    }
    const unsigned short* We = Wt + (long)e * NC * K;
    const unsigned short* pB[LB];
#pragma unroll
    for (int i = 0; i < LB; ++i) {
        const int r = wid * (BN_ / 4) + i * 8 + lr;
        pB[i] = (const unsigned short*)((const char*)(We + (long)(n0 + r) * K) + sb);
    }

    const int wm = (wid >> 1) * (BM_ / 2);
    const int wn = (wid & 1) * (BN_ / 2);
    const int hk = 16 * (lane >> 4);

    const f32x4 zero4 = {0.f, 0.f, 0.f, 0.f};
    f32x4 acc[FM][FN];
#pragma unroll
    for (int i = 0; i < FM; ++i)
#pragma unroll
        for (int j = 0; j < FN; ++j) acc[i][j] = zero4;

    for (int t = 0; t < NT; ++t) {
        __syncthreads();   // prior-iter readers done
#pragma unroll
        for (int i = 0; i < LA; ++i)
            __builtin_amdgcn_global_load_lds((gas_t*)(pA[i] + t * 64),
                (las_t*)(Asb + (wid * (BM_ / 4) + i * 8) * 64), 16, 0, 0);
#pragma unroll
        for (int i = 0; i < LB; ++i)
            __builtin_amdgcn_global_load_lds((gas_t*)(pB[i] + t * 64),
                (las_t*)(Btb + (wid * (BN_ / 4) + i * 8) * 64), 16, 0, 0);
        __syncthreads();   // staging complete
#pragma unroll
        for (int kk = 0; kk < BK; kk += 32) {
            bf16x8 a[FM], b[FN];
#pragma unroll
            for (int mf = 0; mf < FM; ++mf) {
                const int r  = wm + mf * 16 + (lane & 15);
                const int kb = (2 * kk + hk) ^ ((r & 7) << 4);
                a[mf] = *(const bf16x8*)((const char*)Asb + r * 128 + kb);
            }
#pragma unroll
            for (int nf = 0; nf < FN; ++nf) {
                const int cc = wn + nf * 16 + (lane & 15);
                const int kb = (2 * kk + hk) ^ ((cc & 7) << 4);
                b[nf] = *(const bf16x8*)((const char*)Btb + cc * 128 + kb);
            }
            __builtin_amdgcn_s_setprio(1);
#pragma unroll
            for (int mf = 0; mf < FM; ++mf)
#pragma unroll
                for (int nf = 0; nf < FN; ++nf)
                    acc[mf][nf] = __builtin_amdgcn_mfma_f32_16x16x32_bf16(
                        a[mf], b[nf], acc[mf][nf], 0, 0, 0);
            __builtin_amdgcn_s_setprio(0);
        }
    }

    // ---- epilogue ----
    if constexpr (MODE == 0) {
        // Two 64-row passes: writer waves (wm==p*64) gelu->bf16 into sh[64][EP],
        // then all 256 threads store 16B-coalesced (keeps LDS at exactly 32KB).
        float bvv[FN];
#pragma unroll
        for (int nf = 0; nf < FN; ++nf)
            bvv[nf] = bias[(long)e * NC + n0 + wn + nf * 16 + (lane & 15)];
#pragma unroll
        for (int p = 0; p < 2; ++p) {
            __syncthreads();   // prior readers of sh done
            if ((wid >> 1) == p) {
#pragma unroll
                for (int nf = 0; nf < FN; ++nf) {
                    const int cl = wn + nf * 16 + (lane & 15);
#pragma unroll
                    for (int mf = 0; mf < FM; ++mf) {
#pragma unroll
                        for (int ri = 0; ri < 4; ++ri) {
                            const int rl = mf * 16 + (lane >> 4) * 4 + ri;
                            sh[rl * EP + cl] = f2bf(gelu_f(acc[mf][nf][ri] + bvv[nf]));
                        }
                    }
                }
            }
            __syncthreads();
            const int row_l = tid >> 2, q = tid & 3;
            const int grow = m0 + p * 64 + row_l;
            if (grow < cnt) {
                char* dst = (char*)(Hout + (long)(base + grow) * HDIM + n0 + q * 32);
                const char* srcp = (const char*)sh + row_l * (EP * 2) + q * 64;
#pragma unroll
                for (int j = 0; j < 4; ++j)
                    *(int4*)(dst + j * 16) = *(const int4*)(srcp + j * 16);
            }
        }
    } else {
#pragma unroll
        for (int nf = 0; nf < FN; ++nf) {
            const int coln = n0 + wn + nf * 16 + (lane & 15);
            const float bv = bias[(long)e * NC + coln];
#pragma unroll
            for (int mf = 0; mf < FM; ++mf) {
                const int rb = m0 + wm + mf * 16 + (lane >> 4) * 4;
#pragma unroll
                for (int ri = 0; ri < 4; ++ri) {
                    const int row = rb + ri;
                    if (row < cnt)
                        Yout[(long)list[base + row] * DDIM + coln] = acc[mf][nf][ri] + bv;
                }
            }
        }
    }
}

extern "C" void kernel_launch(void* const* d_in, const int* in_sizes, int n_in,
                              void* d_out, int out_size, void* d_ws, size_t ws_size,
                              hipStream_t stream) {
    const float* x      = (const float*)d_in[0];
    const float* gate_w = (const float*)d_in[1];
    const float* gate_b = (const float*)d_in[2];
    const float* w1     = (const float*)d_in[3];
    const float* b1     = (const float*)d_in[4];
    const float* w2     = (const float*)d_in[5];
    const float* b2     = (const float*)d_in[6];
    float* out = (float*)d_out;

    // workspace layout
    char* ws = (char*)d_ws;
    int* counts  = (int*)(ws);                 // 8
    int* cur     = (int*)(ws + 128);           // 8
    int* offs    = (int*)(ws + 256);           // 9
    int* t0      = (int*)(ws + 512);           // T0MAX
    int* t1      = (int*)(ws + 768);           // T1MAX
    int* sel     = (int*)(ws + 4096);          // 4096
    int* list    = (int*)(ws + 20480);         // 4096
    unsigned short* xb  = (unsigned short*)(ws + 65536);                      // 8 MB
    unsigned short* Hws = (unsigned short*)(ws + 65536 + 8388608);            // 33.5 MB
    unsigned short* Wtb = (unsigned short*)(ws + 65536 + 8388608 + 33554432); // 67 MB (W1t then W2t)
    const size_t WS_NEEDED = 65536 + 8388608 + 33554432 + 67108864;
    if (ws_size < WS_NEEDED) return;  // deterministic fail, no corruption

    hipMemsetAsync(ws, 0, 256, stream);   // counts + cur
    k_gate<<<NTOK / 4, 256, 0, stream>>>(x, gate_w, gate_b, xb, sel, counts);
    k_fill<<<(NTOK + 255) / 256, 256, 0, stream>>>(sel, counts, cur, offs, list, t0, t1,
                                                   out + (long)NTOK * DDIM);

    // W1t = transpose-convert(w1); FFN up+gelu: 128x128 tiles, compact grid
    k_cvt_w<DDIM, HDIM><<<dim3(HDIM / 64, NEXP * (DDIM / 64)), 256, 0, stream>>>(w1, Wtb);
    k_gemm<0, 128, 128><<<dim3(HDIM / 128, T0MAX), 256, 0, stream>>>(
        xb, Wtb, b1, Hws, nullptr, counts, offs, list, t0);

    // W2t = transpose-convert(w2) into same buffer; FFN down: 64x64 tiles, compact grid
    k_cvt_w<HDIM, DDIM><<<dim3(DDIM / 64, NEXP * (HDIM / 64)), 256, 0, stream>>>(w2, Wtb);
    k_gemm<1, 64, 64><<<dim3(DDIM / 64, T1MAX), 256, 0, stream>>>(
        Hws, Wtb, b2, nullptr, out, counts, offs, list, t1);
}

// Round 7
// 285.154 us; speedup vs baseline: 1.0207x; 1.0207x over previous
//
#include <hip/hip_runtime.h>
#include <math.h>

#define NTOK 4096
#define DDIM 1024
#define HDIM 4096
#define NEXP 8
#define BK 64
#define T0MAX 40   // >= NTOK/128 + NEXP-1 live tiles for GEMM0
#define T1MAX 72   // >= NTOK/64  + NEXP-1 live tiles for GEMM1

typedef float f32x4 __attribute__((ext_vector_type(4)));
typedef __bf16 bf16x8 __attribute__((ext_vector_type(8)));
typedef const __attribute__((address_space(1))) void gas_t;
typedef __attribute__((address_space(3))) void las_t;

__device__ __forceinline__ unsigned short f2bf(float f) {
    union { float f; unsigned u; } v; v.f = f;
    unsigned u = v.u;
    return (unsigned short)((u + 0x7fffu + ((u >> 16) & 1u)) >> 16);
}

__device__ __forceinline__ float gelu_f(float v) {
    return 0.5f * v * (1.0f + erff(v * 0.70710678118654752f));
}

// ---------------- gating: one wave per token (also emits xb = bf16(x)) ----------------
__global__ void k_gate(const float* __restrict__ x, const float* __restrict__ gw,
                       const float* __restrict__ gb, unsigned short* __restrict__ xb,
                       int* __restrict__ sel, int* __restrict__ counts) {
    const int wid = threadIdx.x >> 6, lane = threadIdx.x & 63;
    const int tok = blockIdx.x * 4 + wid;
    const float* xr = x + (long)tok * DDIM;
    unsigned short* xbr = xb + (long)tok * DDIM;
    float s[NEXP];
#pragma unroll
    for (int e = 0; e < NEXP; ++e) s[e] = 0.f;
    for (int it = 0; it < DDIM / 64; ++it) {
        const int kk = it * 64 + lane;
        const float xv = xr[kk];
        xbr[kk] = f2bf(xv);
        const float4* g4 = (const float4*)(gw + (long)kk * NEXP);
        const float4 g0 = g4[0], g1 = g4[1];
        s[0] += xv * g0.x; s[1] += xv * g0.y; s[2] += xv * g0.z; s[3] += xv * g0.w;
        s[4] += xv * g1.x; s[5] += xv * g1.y; s[6] += xv * g1.z; s[7] += xv * g1.w;
    }
#pragma unroll
    for (int e = 0; e < NEXP; ++e)
        for (int off = 32; off > 0; off >>= 1)
            s[e] += __shfl_down(s[e], off);
    if (lane == 0) {
        float best = s[0] + gb[0]; int bi = 0;
#pragma unroll
        for (int e = 1; e < NEXP; ++e) {
            const float v = s[e] + gb[e];
            if (v > best) { best = v; bi = e; }   // strict > keeps lowest index (np.argmax)
        }
        sel[tok] = bi;
        atomicAdd(&counts[bi], 1);
    }
}

// ---------------- fill token lists + scan + live-tile tables ----------------
__global__ void k_fill(const int* __restrict__ sel, const int* __restrict__ counts,
                       int* __restrict__ cur, int* __restrict__ offs,
                       int* __restrict__ list, int* __restrict__ t0,
                       int* __restrict__ t1, float* __restrict__ laux) {
    const int t = blockIdx.x * blockDim.x + threadIdx.x;
    if (t < NTOK) {
        const int e = sel[t];
        int off_e = 0;
#pragma unroll
        for (int j = 0; j < NEXP; ++j) off_e += (j < e) ? counts[j] : 0;  // no array (rule #20)
        list[off_e + atomicAdd(&cur[e], 1)] = t;
    }
    if (t == 0) {
        int o = 0;
        for (int e = 0; e < NEXP; ++e) { offs[e] = o; o += counts[e]; }
        offs[NEXP] = o;
        int i0 = 0;
        for (int e = 0; e < NEXP; ++e)
            for (int m = 0; m < counts[e]; m += 128) t0[i0++] = (e << 16) | m;
        while (i0 < T0MAX) t0[i0++] = -1;
        int i1 = 0;
        for (int e = 0; e < NEXP; ++e)
            for (int m = 0; m < counts[e]; m += 64) t1[i1++] = (e << 16) | m;
        while (i1 < T1MAX) t1[i1++] = -1;
        laux[0] = 0.f;
    }
}

// ---------------- W [e][K][NC] f32 -> Wt [e][NC][K] bf16 (transpose-convert) ----------------
template<int K, int NC>
__global__ __launch_bounds__(256) void k_cvt_w(const float* __restrict__ W,
                                               unsigned short* __restrict__ Wt) {
    __shared__ unsigned short T[64 * 68];   // [n][k], stride 68 breaks bank conflicts
    const int ktiles = K / 64;
    const int e  = blockIdx.y / ktiles;
    const int k0 = (blockIdx.y % ktiles) * 64;
    const int n0 = blockIdx.x * 64;
    const float* src = W + (long)e * K * NC + (long)k0 * NC + n0;
    const int tid = threadIdx.x;
#pragma unroll
    for (int i = 0; i < 4; ++i) {
        const int idx = tid + i * 256;
        const int k = idx >> 4, c4 = (idx & 15) * 4;
        const float4 v = *(const float4*)(src + (long)k * NC + c4);
        T[(c4 + 0) * 68 + k] = f2bf(v.x);
        T[(c4 + 1) * 68 + k] = f2bf(v.y);
        T[(c4 + 2) * 68 + k] = f2bf(v.z);
        T[(c4 + 3) * 68 + k] = f2bf(v.w);
    }
    __syncthreads();
    unsigned short* dst = Wt + (long)e * NC * K + (long)n0 * K + k0;
#pragma unroll
    for (int i = 0; i < 2; ++i) {
        const int idx = tid + i * 256;
        const int n = idx >> 3, c8 = (idx & 7) * 8;
        *(ushort4*)(dst + (long)n * K + c8)     = *(const ushort4*)&T[n * 68 + c8];
        *(ushort4*)(dst + (long)n * K + c8 + 4) = *(const ushort4*)&T[n * 68 + c8 + 4];
    }
}

// ---------------- grouped GEMM: dbuf + COUNTED-vmcnt pipeline + compact grid ----------
// 256 thr = 4 waves, per-wave (BM/2)x(BN/2). Double-buffered LDS, XOR swizzle via
// pre-swizzled global source, global_load_lds w=16, compact ttab grid (~95% live).
// K-loop (T4): prologue stages tiles 0,1; per iter:
//   vmcnt(LA+LB)  [tile t landed; t+1 stays in flight]  -> s_barrier
//   ds_read+MFMA(buf t&1) -> s_barrier -> STAGE(t+2 -> buf t&1)
// vmcnt(0) only at the final iteration. Raw barriers never drain the prefetch.
template<int MODE, int BM_, int BN_>
__global__ __launch_bounds__(256) void k_gemm(
        const unsigned short* __restrict__ Ain,
        const unsigned short* __restrict__ Wt,
        const float* __restrict__ bias,
        unsigned short* __restrict__ Hout, float* __restrict__ Yout,
        const int* __restrict__ counts, const int* __restrict__ offs,
        const int* __restrict__ list, const int* __restrict__ ttab) {
    static_assert(BM_ % 32 == 0 && BN_ % 32 == 0, "tile");
    constexpr int K    = (MODE == 0) ? DDIM : HDIM;
    constexpr int NC   = (MODE == 0) ? HDIM : DDIM;
    constexpr int NT   = K / BK;
    constexpr int FM   = BM_ / 32;
    constexpr int FN   = BN_ / 32;
    constexpr int LA   = BM_ / 32;     // A loads per thread per tile
    constexpr int LB   = BN_ / 32;
    constexpr int HALF = BM_ * 64 + BN_ * 64;     // one stage buffer (shorts)
    constexpr int EP   = 136;                     // MODE0 epilogue stride (shorts)
    constexpr int SH_SZ = (2 * HALF > BM_ * EP) ? 2 * HALF : BM_ * EP;

    const int code = ttab[blockIdx.y];
    if (code < 0) return;
    const int e  = code >> 16;
    const int m0 = code & 0xFFFF;
    const int cnt  = counts[e];
    const int base = offs[e];
    const int n0   = blockIdx.x * BN_;

    __shared__ __align__(16) unsigned short sh[SH_SZ];

    const int tid  = threadIdx.x;
    const int lane = tid & 63, wid = tid >> 6;
    const int lr = lane >> 3, lc = lane & 7;
    const int sb = (lc * 16) ^ (lr << 4);        // pre-swizzled source byte offset

    const unsigned short* pA[LA];
#pragma unroll
    for (int i = 0; i < LA; ++i) {
        const int r = wid * (BM_ / 4) + i * 8 + lr;
        int rr = m0 + r; if (rr >= cnt) rr = cnt - 1;
        const long grow = (MODE == 0) ? (long)list[base + rr] : (long)(base + rr);
        pA[i] = (const unsigned short*)((const char*)(Ain + grow * K) + sb);
    }
    const unsigned short* We = Wt + (long)e * NC * K;
    const unsigned short* pB[LB];
#pragma unroll
    for (int i = 0; i < LB; ++i) {
        const int r = wid * (BN_ / 4) + i * 8 + lr;
        pB[i] = (const unsigned short*)((const char*)(We + (long)(n0 + r) * K) + sb);
    }

    const int wm = (wid >> 1) * (BM_ / 2);
    const int wn = (wid & 1) * (BN_ / 2);
    const int hk = 16 * (lane >> 4);

#define STAGE(t) do { if ((t) < NT) {                                                    \
    unsigned short* Ad = sh + ((t) & 1) * HALF + (wid * (BM_ / 4)) * 64;                 \
    unsigned short* Bd = sh + ((t) & 1) * HALF + BM_ * 64 + (wid * (BN_ / 4)) * 64;      \
    _Pragma("unroll") for (int i = 0; i < LA; ++i)                                       \
        __builtin_amdgcn_global_load_lds((gas_t*)(pA[i] + (t) * 64),                     \
            (las_t*)(Ad + i * 512), 16, 0, 0);                                           \
    _Pragma("unroll") for (int i = 0; i < LB; ++i)                                       \
        __builtin_amdgcn_global_load_lds((gas_t*)(pB[i] + (t) * 64),                     \
            (las_t*)(Bd + i * 512), 16, 0, 0); } } while (0)

    const f32x4 zero4 = {0.f, 0.f, 0.f, 0.f};
    f32x4 acc[FM][FN];
#pragma unroll
    for (int i = 0; i < FM; ++i)
#pragma unroll
        for (int j = 0; j < FN; ++j) acc[i][j] = zero4;

    STAGE(0);
    STAGE(1);

    for (int t = 0; t < NT; ++t) {
        const unsigned short* Ab = sh + (t & 1) * HALF;
        const unsigned short* Bb = Ab + BM_ * 64;
        // wait for tile t's loads only; tile t+1's stay in flight across the barrier
        if (t + 1 < NT) { asm volatile("s_waitcnt vmcnt(%0)" :: "n"(LA + LB) : "memory"); }
        else            { asm volatile("s_waitcnt vmcnt(0)" ::: "memory"); }
        __builtin_amdgcn_sched_barrier(0);
        __builtin_amdgcn_s_barrier();
        __builtin_amdgcn_sched_barrier(0);
#pragma unroll
        for (int kk = 0; kk < BK; kk += 32) {
            bf16x8 a[FM], b[FN];
#pragma unroll
            for (int mf = 0; mf < FM; ++mf) {
                const int r  = wm + mf * 16 + (lane & 15);
                const int kb = (2 * kk + hk) ^ ((r & 7) << 4);
                a[mf] = *(const bf16x8*)((const char*)Ab + r * 128 + kb);
            }
#pragma unroll
            for (int nf = 0; nf < FN; ++nf) {
                const int cc = wn + nf * 16 + (lane & 15);
                const int kb = (2 * kk + hk) ^ ((cc & 7) << 4);
                b[nf] = *(const bf16x8*)((const char*)Bb + cc * 128 + kb);
            }
            __builtin_amdgcn_s_setprio(1);
#pragma unroll
            for (int mf = 0; mf < FM; ++mf)
#pragma unroll
                for (int nf = 0; nf < FN; ++nf)
                    acc[mf][nf] = __builtin_amdgcn_mfma_f32_16x16x32_bf16(
                        a[mf], b[nf], acc[mf][nf], 0, 0, 0);
            __builtin_amdgcn_s_setprio(0);
        }
        __builtin_amdgcn_sched_barrier(0);
        __builtin_amdgcn_s_barrier();   // all reads of buf (t&1) done -> safe to overwrite
        __builtin_amdgcn_sched_barrier(0);
        STAGE(t + 2);
    }
#undef STAGE

    // ---- epilogue ----
    if constexpr (MODE == 0) {
        // bias+gelu -> bf16 tile in LDS ([BM][EP=136] shorts, 272B rows, 16B-aligned),
        // then 16B coalesced stores. Final in-loop barrier ensured sh reads are done;
        // vmcnt(0) at t=NT-1 ensured no in-flight LDS writes.
#pragma unroll
        for (int nf = 0; nf < FN; ++nf) {
            const int cl = wn + nf * 16 + (lane & 15);
            const float bv = bias[(long)e * NC + n0 + cl];
#pragma unroll
            for (int mf = 0; mf < FM; ++mf) {
#pragma unroll
                for (int ri = 0; ri < 4; ++ri) {
                    const int rl = wm + mf * 16 + (lane >> 4) * 4 + ri;
                    sh[rl * EP + cl] = f2bf(gelu_f(acc[mf][nf][ri] + bv));
                }
            }
        }
        __syncthreads();
        const int row = tid >> 1, ch = (tid & 1) * 64;
        if (m0 + row < cnt) {
            char* dst = (char*)(Hout + (long)(base + m0 + row) * HDIM + n0 + ch);
            const char* srcp = (const char*)sh + row * (EP * 2) + ch * 2;
#pragma unroll
            for (int j = 0; j < 4; ++j) {
                const int4 v0 = *(const int4*)(srcp + j * 32);
                const int4 v1 = *(const int4*)(srcp + j * 32 + 16);
                *(int4*)(dst + j * 32)      = v0;
                *(int4*)(dst + j * 32 + 16) = v1;
            }
        }
    } else {
#pragma unroll
        for (int nf = 0; nf < FN; ++nf) {
            const int coln = n0 + wn + nf * 16 + (lane & 15);
            const float bv = bias[(long)e * NC + coln];
#pragma unroll
            for (int mf = 0; mf < FM; ++mf) {
                const int rb = m0 + wm + mf * 16 + (lane >> 4) * 4;
#pragma unroll
                for (int ri = 0; ri < 4; ++ri) {
                    const int row = rb + ri;
                    if (row < cnt)
                        Yout[(long)list[base + row] * DDIM + coln] = acc[mf][nf][ri] + bv;
                }
            }
        }
    }
}

extern "C" void kernel_launch(void* const* d_in, const int* in_sizes, int n_in,
                              void* d_out, int out_size, void* d_ws, size_t ws_size,
                              hipStream_t stream) {
    const float* x      = (const float*)d_in[0];
    const float* gate_w = (const float*)d_in[1];
    const float* gate_b = (const float*)d_in[2];
    const float* w1     = (const float*)d_in[3];
    const float* b1     = (const float*)d_in[4];
    const float* w2     = (const float*)d_in[5];
    const float* b2     = (const float*)d_in[6];
    float* out = (float*)d_out;

    // workspace layout
    char* ws = (char*)d_ws;
    int* counts  = (int*)(ws);                 // 8
    int* cur     = (int*)(ws + 128);           // 8
    int* offs    = (int*)(ws + 256);           // 9
    int* t0      = (int*)(ws + 512);           // T0MAX
    int* t1      = (int*)(ws + 768);           // T1MAX
    int* sel     = (int*)(ws + 4096);          // 4096
    int* list    = (int*)(ws + 20480);         // 4096
    unsigned short* xb  = (unsigned short*)(ws + 65536);                      // 8 MB
    unsigned short* Hws = (unsigned short*)(ws + 65536 + 8388608);            // 33.5 MB
    unsigned short* Wtb = (unsigned short*)(ws + 65536 + 8388608 + 33554432); // 67 MB (W1t then W2t)
    const size_t WS_NEEDED = 65536 + 8388608 + 33554432 + 67108864;
    if (ws_size < WS_NEEDED) return;  // deterministic fail, no corruption

    hipMemsetAsync(ws, 0, 256, stream);   // counts + cur
    k_gate<<<NTOK / 4, 256, 0, stream>>>(x, gate_w, gate_b, xb, sel, counts);
    k_fill<<<(NTOK + 255) / 256, 256, 0, stream>>>(sel, counts, cur, offs, list, t0, t1,
                                                   out + (long)NTOK * DDIM);

    // W1t = transpose-convert(w1); FFN up+gelu: 128x128 tiles, counted-vmcnt dbuf
    k_cvt_w<DDIM, HDIM><<<dim3(HDIM / 64, NEXP * (DDIM / 64)), 256, 0, stream>>>(w1, Wtb);
    k_gemm<0, 128, 128><<<dim3(HDIM / 128, T0MAX), 256, 0, stream>>>(
        xb, Wtb, b1, Hws, nullptr, counts, offs, list, t0);

    // W2t = transpose-convert(w2) into same buffer; FFN down: 64x64 tiles, counted-vmcnt dbuf
    k_cvt_w<HDIM, DDIM><<<dim3(DDIM / 64, NEXP * (HDIM / 64)), 256, 0, stream>>>(w2, Wtb);
    k_gemm<1, 64, 64><<<dim3(DDIM / 64, T1MAX), 256, 0, stream>>>(
        Hws, Wtb, b2, nullptr, out, counts, offs, list, t1);
}

// Round 8
// 279.236 us; speedup vs baseline: 1.0423x; 1.0212x over previous
//
#include <hip/hip_runtime.h>
#include <math.h>

#define NTOK 4096
#define DDIM 1024
#define HDIM 4096
#define NEXP 8
#define BK 64
#define T0MAX 40   // >= NTOK/128 + NEXP-1 live tiles for GEMM0
#define T1MAX 72   // >= NTOK/64  + NEXP-1 live tiles for GEMM1
#define NG0 ((HDIM / 128) * T0MAX)          // 1280 gemm0 blocks
#define NCVT2 ((DDIM / 64) * (NEXP * (HDIM / 64)))  // 8192 cvt_w2 blocks

typedef float f32x4 __attribute__((ext_vector_type(4)));
typedef __bf16 bf16x8 __attribute__((ext_vector_type(8)));
typedef const __attribute__((address_space(1))) void gas_t;
typedef __attribute__((address_space(3))) void las_t;

__device__ __forceinline__ unsigned short f2bf(float f) {
    union { float f; unsigned u; } v; v.f = f;
    unsigned u = v.u;
    return (unsigned short)((u + 0x7fffu + ((u >> 16) & 1u)) >> 16);
}

__device__ __forceinline__ float gelu_f(float v) {
    return 0.5f * v * (1.0f + erff(v * 0.70710678118654752f));
}

// ---------------- gating: one wave per token (also emits xb = bf16(x)) ----------------
// float4 x loads (16B/lane), ushort4 xb stores.
__global__ void k_gate(const float* __restrict__ x, const float* __restrict__ gw,
                       const float* __restrict__ gb, unsigned short* __restrict__ xb,
                       int* __restrict__ sel, int* __restrict__ counts) {
    const int wid = threadIdx.x >> 6, lane = threadIdx.x & 63;
    const int tok = blockIdx.x * 4 + wid;
    const float4* xr4 = (const float4*)(x + (long)tok * DDIM);
    unsigned short* xbr = xb + (long)tok * DDIM;
    float s[NEXP];
#pragma unroll
    for (int e = 0; e < NEXP; ++e) s[e] = 0.f;
#pragma unroll
    for (int it = 0; it < DDIM / 256; ++it) {
        const int q = it * 64 + lane;            // float4 index
        const float4 xv = xr4[q];
        *(ushort4*)(xbr + q * 4) = make_ushort4(f2bf(xv.x), f2bf(xv.y), f2bf(xv.z), f2bf(xv.w));
#pragma unroll
        for (int j = 0; j < 4; ++j) {
            const float xs = (j == 0) ? xv.x : (j == 1) ? xv.y : (j == 2) ? xv.z : xv.w;
            const float4* g4 = (const float4*)(gw + (long)(q * 4 + j) * NEXP);
            const float4 g0 = g4[0], g1 = g4[1];
            s[0] += xs * g0.x; s[1] += xs * g0.y; s[2] += xs * g0.z; s[3] += xs * g0.w;
            s[4] += xs * g1.x; s[5] += xs * g1.y; s[6] += xs * g1.z; s[7] += xs * g1.w;
        }
    }
#pragma unroll
    for (int e = 0; e < NEXP; ++e)
        for (int off = 32; off > 0; off >>= 1)
            s[e] += __shfl_down(s[e], off);
    if (lane == 0) {
        float best = s[0] + gb[0]; int bi = 0;
#pragma unroll
        for (int e = 1; e < NEXP; ++e) {
            const float v = s[e] + gb[e];
            if (v > best) { best = v; bi = e; }   // strict > keeps lowest index (np.argmax)
        }
        sel[tok] = bi;
        atomicAdd(&counts[bi], 1);
    }
}

// ---------------- fill token lists + scan + live-tile tables ----------------
__global__ void k_fill(const int* __restrict__ sel, const int* __restrict__ counts,
                       int* __restrict__ cur, int* __restrict__ offs,
                       int* __restrict__ list, int* __restrict__ t0,
                       int* __restrict__ t1, float* __restrict__ laux) {
    const int t = blockIdx.x * blockDim.x + threadIdx.x;
    if (t < NTOK) {
        const int e = sel[t];
        int off_e = 0;
#pragma unroll
        for (int j = 0; j < NEXP; ++j) off_e += (j < e) ? counts[j] : 0;  // no array (rule #20)
        list[off_e + atomicAdd(&cur[e], 1)] = t;
    }
    if (t == 0) {
        int o = 0;
        for (int e = 0; e < NEXP; ++e) { offs[e] = o; o += counts[e]; }
        offs[NEXP] = o;
        int i0 = 0;
        for (int e = 0; e < NEXP; ++e)
            for (int m = 0; m < counts[e]; m += 128) t0[i0++] = (e << 16) | m;
        while (i0 < T0MAX) t0[i0++] = -1;
        int i1 = 0;
        for (int e = 0; e < NEXP; ++e)
            for (int m = 0; m < counts[e]; m += 64) t1[i1++] = (e << 16) | m;
        while (i1 < T1MAX) t1[i1++] = -1;
        laux[0] = 0.f;
    }
}

// ---------------- W tile transpose-convert (device body, LDS passed in) ----------------
template<int K, int NC>
__device__ __forceinline__ void cvt_tile(const float* __restrict__ W,
                                         unsigned short* __restrict__ Wt,
                                         int bx, int by, unsigned short* T) {
    constexpr int ktiles = K / 64;
    const int e  = by / ktiles;
    const int k0 = (by % ktiles) * 64;
    const int n0 = bx * 64;
    const float* src = W + (long)e * K * NC + (long)k0 * NC + n0;
    const int tid = threadIdx.x;
#pragma unroll
    for (int i = 0; i < 4; ++i) {
        const int idx = tid + i * 256;
        const int k = idx >> 4, c4 = (idx & 15) * 4;
        const float4 v = *(const float4*)(src + (long)k * NC + c4);
        T[(c4 + 0) * 68 + k] = f2bf(v.x);
        T[(c4 + 1) * 68 + k] = f2bf(v.y);
        T[(c4 + 2) * 68 + k] = f2bf(v.z);
        T[(c4 + 3) * 68 + k] = f2bf(v.w);
    }
    __syncthreads();
    unsigned short* dst = Wt + (long)e * NC * K + (long)n0 * K + k0;
#pragma unroll
    for (int i = 0; i < 2; ++i) {
        const int idx = tid + i * 256;
        const int n = idx >> 3, c8 = (idx & 7) * 8;
        *(ushort4*)(dst + (long)n * K + c8)     = *(const ushort4*)&T[n * 68 + c8];
        *(ushort4*)(dst + (long)n * K + c8 + 4) = *(const ushort4*)&T[n * 68 + c8 + 4];
    }
}

// ---------------- standalone transpose-convert kernel ----------------
template<int K, int NC>
__global__ __launch_bounds__(256) void k_cvt_w(const float* __restrict__ W,
                                               unsigned short* __restrict__ Wt) {
    __shared__ unsigned short T[64 * 68];
    cvt_tile<K, NC>(W, Wt, blockIdx.x, blockIdx.y, T);
}

// ---------------- grouped GEMM: dbuf + counted-vmcnt pipeline + compact grid ----------
// Same verified R7 K-loop. FUSE adds heterogeneous cvt_w2 blocks (IDs >= NG0) that
// transpose-convert w2 -> W2t while the gemm blocks compute: BW-bound cvt streams
// through the HBM slack of the compute-bound gemm (single launch = true overlap).
template<int MODE, int BM_, int BN_, bool FUSE>
__global__ __launch_bounds__(256) void k_gemm(
        const unsigned short* __restrict__ Ain,
        const unsigned short* __restrict__ Wt,
        const float* __restrict__ bias,
        unsigned short* __restrict__ Hout, float* __restrict__ Yout,
        const int* __restrict__ counts, const int* __restrict__ offs,
        const int* __restrict__ list, const int* __restrict__ ttab,
        const float* __restrict__ Wcvt, unsigned short* __restrict__ Wtcvt) {
    static_assert(BM_ % 32 == 0 && BN_ % 32 == 0, "tile");
    constexpr int K    = (MODE == 0) ? DDIM : HDIM;
    constexpr int NC   = (MODE == 0) ? HDIM : DDIM;
    constexpr int NT   = K / BK;
    constexpr int FM   = BM_ / 32;
    constexpr int FN   = BN_ / 32;
    constexpr int LA   = BM_ / 32;     // A loads per thread per tile
    constexpr int LB   = BN_ / 32;
    constexpr int HALF = BM_ * 64 + BN_ * 64;     // one stage buffer (shorts)
    constexpr int EP   = 136;                     // MODE0 epilogue stride (shorts)
    constexpr int SH_SZ = (2 * HALF > BM_ * EP) ? 2 * HALF : BM_ * EP;

    __shared__ __align__(16) unsigned short sh[SH_SZ];

    int bx, by;
    if constexpr (FUSE) {
        const int bid = blockIdx.x;
        if (bid >= NG0) {                         // cvt_w2 block
            const int cv = bid - NG0;
            cvt_tile<HDIM, DDIM>(Wcvt, Wtcvt, cv % (DDIM / 64), cv / (DDIM / 64), sh);
            return;
        }
        bx = bid % (NC / BN_); by = bid / (NC / BN_);
    } else {
        bx = blockIdx.x; by = blockIdx.y;
    }

    const int code = ttab[by];
    if (code < 0) return;
    const int e  = code >> 16;
    const int m0 = code & 0xFFFF;
    const int cnt  = counts[e];
    const int base = offs[e];
    const int n0   = bx * BN_;

    const int tid  = threadIdx.x;
    const int lane = tid & 63, wid = tid >> 6;
    const int lr = lane >> 3, lc = lane & 7;
    const int sb = (lc * 16) ^ (lr << 4);        // pre-swizzled source byte offset

    const unsigned short* pA[LA];
#pragma unroll
    for (int i = 0; i < LA; ++i) {
        const int r = wid * (BM_ / 4) + i * 8 + lr;
        int rr = m0 + r; if (rr >= cnt) rr = cnt - 1;
        const long grow = (MODE == 0) ? (long)list[base + rr] : (long)(base + rr);
        pA[i] = (const unsigned short*)((const char*)(Ain + grow * K) + sb);
    }
    const unsigned short* We = Wt + (long)e * NC * K;
    const unsigned short* pB[LB];
#pragma unroll
    for (int i = 0; i < LB; ++i) {
        const int r = wid * (BN_ / 4) + i * 8 + lr;
        pB[i] = (const unsigned short*)((const char*)(We + (long)(n0 + r) * K) + sb);
    }

    const int wm = (wid >> 1) * (BM_ / 2);
    const int wn = (wid & 1) * (BN_ / 2);
    const int hk = 16 * (lane >> 4);

#define STAGE(t) do { if ((t) < NT) {                                                    \
    unsigned short* Ad = sh + ((t) & 1) * HALF + (wid * (BM_ / 4)) * 64;                 \
    unsigned short* Bd = sh + ((t) & 1) * HALF + BM_ * 64 + (wid * (BN_ / 4)) * 64;      \
    _Pragma("unroll") for (int i = 0; i < LA; ++i)                                       \
        __builtin_amdgcn_global_load_lds((gas_t*)(pA[i] + (t) * 64),                     \
            (las_t*)(Ad + i * 512), 16, 0, 0);                                           \
    _Pragma("unroll") for (int i = 0; i < LB; ++i)                                       \
        __builtin_amdgcn_global_load_lds((gas_t*)(pB[i] + (t) * 64),                     \
            (las_t*)(Bd + i * 512), 16, 0, 0); } } while (0)

    const f32x4 zero4 = {0.f, 0.f, 0.f, 0.f};
    f32x4 acc[FM][FN];
#pragma unroll
    for (int i = 0; i < FM; ++i)
#pragma unroll
        for (int j = 0; j < FN; ++j) acc[i][j] = zero4;

    STAGE(0);
    STAGE(1);

    for (int t = 0; t < NT; ++t) {
        const unsigned short* Ab = sh + (t & 1) * HALF;
        const unsigned short* Bb = Ab + BM_ * 64;
        // wait for tile t's loads only; tile t+1's stay in flight across the barrier
        if (t + 1 < NT) { asm volatile("s_waitcnt vmcnt(%0)" :: "n"(LA + LB) : "memory"); }
        else            { asm volatile("s_waitcnt vmcnt(0)" ::: "memory"); }
        __builtin_amdgcn_sched_barrier(0);
        __builtin_amdgcn_s_barrier();
        __builtin_amdgcn_sched_barrier(0);
#pragma unroll
        for (int kk = 0; kk < BK; kk += 32) {
            bf16x8 a[FM], b[FN];
#pragma unroll
            for (int mf = 0; mf < FM; ++mf) {
                const int r  = wm + mf * 16 + (lane & 15);
                const int kb = (2 * kk + hk) ^ ((r & 7) << 4);
                a[mf] = *(const bf16x8*)((const char*)Ab + r * 128 + kb);
            }
#pragma unroll
            for (int nf = 0; nf < FN; ++nf) {
                const int cc = wn + nf * 16 + (lane & 15);
                const int kb = (2 * kk + hk) ^ ((cc & 7) << 4);
                b[nf] = *(const bf16x8*)((const char*)Bb + cc * 128 + kb);
            }
            __builtin_amdgcn_s_setprio(1);
#pragma unroll
            for (int mf = 0; mf < FM; ++mf)
#pragma unroll
                for (int nf = 0; nf < FN; ++nf)
                    acc[mf][nf] = __builtin_amdgcn_mfma_f32_16x16x32_bf16(
                        a[mf], b[nf], acc[mf][nf], 0, 0, 0);
            __builtin_amdgcn_s_setprio(0);
        }
        __builtin_amdgcn_sched_barrier(0);
        __builtin_amdgcn_s_barrier();   // all reads of buf (t&1) done -> safe to overwrite
        __builtin_amdgcn_sched_barrier(0);
        STAGE(t + 2);
    }
#undef STAGE

    // ---- epilogue ----
    if constexpr (MODE == 0) {
#pragma unroll
        for (int nf = 0; nf < FN; ++nf) {
            const int cl = wn + nf * 16 + (lane & 15);
            const float bv = bias[(long)e * NC + n0 + cl];
#pragma unroll
            for (int mf = 0; mf < FM; ++mf) {
#pragma unroll
                for (int ri = 0; ri < 4; ++ri) {
                    const int rl = wm + mf * 16 + (lane >> 4) * 4 + ri;
                    sh[rl * EP + cl] = f2bf(gelu_f(acc[mf][nf][ri] + bv));
                }
            }
        }
        __syncthreads();
        const int row = tid >> 1, ch = (tid & 1) * 64;
        if (m0 + row < cnt) {
            char* dst = (char*)(Hout + (long)(base + m0 + row) * HDIM + n0 + ch);
            const char* srcp = (const char*)sh + row * (EP * 2) + ch * 2;
#pragma unroll
            for (int j = 0; j < 4; ++j) {
                const int4 v0 = *(const int4*)(srcp + j * 32);
                const int4 v1 = *(const int4*)(srcp + j * 32 + 16);
                *(int4*)(dst + j * 32)      = v0;
                *(int4*)(dst + j * 32 + 16) = v1;
            }
        }
    } else {
#pragma unroll
        for (int nf = 0; nf < FN; ++nf) {
            const int coln = n0 + wn + nf * 16 + (lane & 15);
            const float bv = bias[(long)e * NC + coln];
#pragma unroll
            for (int mf = 0; mf < FM; ++mf) {
                const int rb = m0 + wm + mf * 16 + (lane >> 4) * 4;
#pragma unroll
                for (int ri = 0; ri < 4; ++ri) {
                    const int row = rb + ri;
                    if (row < cnt)
                        Yout[(long)list[base + row] * DDIM + coln] = acc[mf][nf][ri] + bv;
                }
            }
        }
    }
}

extern "C" void kernel_launch(void* const* d_in, const int* in_sizes, int n_in,
                              void* d_out, int out_size, void* d_ws, size_t ws_size,
                              hipStream_t stream) {
    const float* x      = (const float*)d_in[0];
    const float* gate_w = (const float*)d_in[1];
    const float* gate_b = (const float*)d_in[2];
    const float* w1     = (const float*)d_in[3];
    const float* b1     = (const float*)d_in[4];
    const float* w2     = (const float*)d_in[5];
    const float* b2     = (const float*)d_in[6];
    float* out = (float*)d_out;

    // workspace layout
    char* ws = (char*)d_ws;
    int* counts  = (int*)(ws);                 // 8
    int* cur     = (int*)(ws + 128);           // 8
    int* offs    = (int*)(ws + 256);           // 9
    int* t0      = (int*)(ws + 512);           // T0MAX
    int* t1      = (int*)(ws + 768);           // T1MAX
    int* sel     = (int*)(ws + 4096);          // 4096
    int* list    = (int*)(ws + 20480);         // 4096
    unsigned short* xb  = (unsigned short*)(ws + 65536);                      // 8 MB
    unsigned short* Hws = (unsigned short*)(ws + 65536 + 8388608);            // 33.5 MB
    unsigned short* W1t = (unsigned short*)(ws + 65536 + 8388608 + 33554432); // 64 MB
    unsigned short* W2s = W1t + (size_t)NEXP * HDIM * DDIM;                   // 64 MB (big path)
    const size_t WS_SMALL = 65536 + 8388608 + 33554432 + 67108864;
    const size_t WS_BIG   = WS_SMALL + 67108864;
    if (ws_size < WS_SMALL) return;  // deterministic fail, no corruption
    const bool big = ws_size >= WS_BIG;
    unsigned short* W2t = big ? W2s : W1t;     // small path reuses W1t region sequentially

    hipMemsetAsync(ws, 0, 256, stream);   // counts + cur
    k_gate<<<NTOK / 4, 256, 0, stream>>>(x, gate_w, gate_b, xb, sel, counts);
    k_fill<<<(NTOK + 255) / 256, 256, 0, stream>>>(sel, counts, cur, offs, list, t0, t1,
                                                   out + (long)NTOK * DDIM);

    // W1t = transpose-convert(w1)
    k_cvt_w<DDIM, HDIM><<<dim3(HDIM / 64, NEXP * (DDIM / 64)), 256, 0, stream>>>(w1, W1t);

    if (big) {
        // FFN up+gelu FUSED with cvt(w2)->W2t: gemm blocks 0..NG0-1, cvt blocks behind
        k_gemm<0, 128, 128, true><<<NG0 + NCVT2, 256, 0, stream>>>(
            xb, W1t, b1, Hws, nullptr, counts, offs, list, t0, w2, W2t);
    } else {
        k_gemm<0, 128, 128, false><<<dim3(HDIM / 128, T0MAX), 256, 0, stream>>>(
            xb, W1t, b1, Hws, nullptr, counts, offs, list, t0, nullptr, nullptr);
        k_cvt_w<HDIM, DDIM><<<dim3(DDIM / 64, NEXP * (HDIM / 64)), 256, 0, stream>>>(w2, W2t);
    }

    // FFN down: 64x64 tiles, counted-vmcnt dbuf, compact grid
    k_gemm<1, 64, 64, false><<<dim3(DDIM / 64, T1MAX), 256, 0, stream>>>(
        Hws, W2t, b2, nullptr, out, counts, offs, list, t1, nullptr, nullptr);
}

// Round 9
// 264.993 us; speedup vs baseline: 1.0984x; 1.0538x over previous
//
#include <hip/hip_runtime.h>
#include <math.h>

#define NTOK 4096
#define DDIM 1024
#define HDIM 4096
#define NEXP 8
#define BK 64
#define T0MAX 40   // >= NTOK/128 + NEXP-1 live tiles for GEMM0
#define T1MAX 72   // >= NTOK/64  + NEXP-1 live tiles for GEMM1
#define NGATE (NTOK / 4)                              // 1024 gate blocks
#define NCVT1 ((HDIM / 64) * (NEXP * (DDIM / 64)))    // 8192 cvt_w1 blocks
#define NG0   ((HDIM / 128) * T0MAX)                  // 1280 gemm0 blocks
#define NCVT2 ((DDIM / 64) * (NEXP * (HDIM / 64)))    // 8192 cvt_w2 blocks

typedef float f32x4 __attribute__((ext_vector_type(4)));
typedef __bf16 bf16x8 __attribute__((ext_vector_type(8)));
typedef const __attribute__((address_space(1))) void gas_t;
typedef __attribute__((address_space(3))) void las_t;

__device__ __forceinline__ unsigned short f2bf(float f) {
    union { float f; unsigned u; } v; v.f = f;
    unsigned u = v.u;
    return (unsigned short)((u + 0x7fffu + ((u >> 16) & 1u)) >> 16);
}

__device__ __forceinline__ float gelu_f(float v) {
    return 0.5f * v * (1.0f + erff(v * 0.70710678118654752f));
}

// ---------------- W tile transpose-convert (device body, LDS passed in) ----------------
template<int K, int NC>
__device__ __forceinline__ void cvt_tile(const float* __restrict__ W,
                                         unsigned short* __restrict__ Wt,
                                         int bx, int by, unsigned short* T) {
    constexpr int ktiles = K / 64;
    const int e  = by / ktiles;
    const int k0 = (by % ktiles) * 64;
    const int n0 = bx * 64;
    const float* src = W + (long)e * K * NC + (long)k0 * NC + n0;
    const int tid = threadIdx.x;
#pragma unroll
    for (int i = 0; i < 4; ++i) {
        const int idx = tid + i * 256;
        const int k = idx >> 4, c4 = (idx & 15) * 4;
        const float4 v = *(const float4*)(src + (long)k * NC + c4);
        T[(c4 + 0) * 68 + k] = f2bf(v.x);
        T[(c4 + 1) * 68 + k] = f2bf(v.y);
        T[(c4 + 2) * 68 + k] = f2bf(v.z);
        T[(c4 + 3) * 68 + k] = f2bf(v.w);
    }
    __syncthreads();
    unsigned short* dst = Wt + (long)e * NC * K + (long)n0 * K + k0;
#pragma unroll
    for (int i = 0; i < 2; ++i) {
        const int idx = tid + i * 256;
        const int n = idx >> 3, c8 = (idx & 7) * 8;
        *(ushort4*)(dst + (long)n * K + c8)     = *(const ushort4*)&T[n * 68 + c8];
        *(ushort4*)(dst + (long)n * K + c8 + 4) = *(const ushort4*)&T[n * 68 + c8 + 4];
    }
}

// ---------------- fused: gating (blocks 0..NGATE-1) + cvt(w1) (blocks behind) ----------
// gate: one wave per token, float4 x loads, emits xb = bf16(x). cvt: W1t transpose.
// Independent ops, both BW-bound; fusing overlaps gate under cvt_w1's stream.
__global__ __launch_bounds__(256) void k_gatecvt(
        const float* __restrict__ x, const float* __restrict__ gw,
        const float* __restrict__ gb, unsigned short* __restrict__ xb,
        int* __restrict__ sel, int* __restrict__ counts,
        const float* __restrict__ w1, unsigned short* __restrict__ W1t) {
    __shared__ unsigned short T[64 * 68];
    const int bid = blockIdx.x;
    if (bid >= NGATE) {
        const int cv = bid - NGATE;
        cvt_tile<DDIM, HDIM>(w1, W1t, cv % (HDIM / 64), cv / (HDIM / 64), T);
        return;
    }
    const int wid = threadIdx.x >> 6, lane = threadIdx.x & 63;
    const int tok = bid * 4 + wid;
    const float4* xr4 = (const float4*)(x + (long)tok * DDIM);
    unsigned short* xbr = xb + (long)tok * DDIM;
    float s[NEXP];
#pragma unroll
    for (int e = 0; e < NEXP; ++e) s[e] = 0.f;
#pragma unroll
    for (int it = 0; it < DDIM / 256; ++it) {
        const int q = it * 64 + lane;            // float4 index
        const float4 xv = xr4[q];
        *(ushort4*)(xbr + q * 4) = make_ushort4(f2bf(xv.x), f2bf(xv.y), f2bf(xv.z), f2bf(xv.w));
#pragma unroll
        for (int j = 0; j < 4; ++j) {
            const float xs = (j == 0) ? xv.x : (j == 1) ? xv.y : (j == 2) ? xv.z : xv.w;
            const float4* g4 = (const float4*)(gw + (long)(q * 4 + j) * NEXP);
            const float4 g0 = g4[0], g1 = g4[1];
            s[0] += xs * g0.x; s[1] += xs * g0.y; s[2] += xs * g0.z; s[3] += xs * g0.w;
            s[4] += xs * g1.x; s[5] += xs * g1.y; s[6] += xs * g1.z; s[7] += xs * g1.w;
        }
    }
#pragma unroll
    for (int e = 0; e < NEXP; ++e)
        for (int off = 32; off > 0; off >>= 1)
            s[e] += __shfl_down(s[e], off);
    if (lane == 0) {
        float best = s[0] + gb[0]; int bi = 0;
#pragma unroll
        for (int e = 1; e < NEXP; ++e) {
            const float v = s[e] + gb[e];
            if (v > best) { best = v; bi = e; }   // strict > keeps lowest index (np.argmax)
        }
        sel[tok] = bi;
        atomicAdd(&counts[bi], 1);
    }
}

// ---------------- fill token lists + scan + live-tile tables ----------------
__global__ void k_fill(const int* __restrict__ sel, const int* __restrict__ counts,
                       int* __restrict__ cur, int* __restrict__ offs,
                       int* __restrict__ list, int* __restrict__ t0,
                       int* __restrict__ t1, float* __restrict__ laux) {
    const int t = blockIdx.x * blockDim.x + threadIdx.x;
    if (t < NTOK) {
        const int e = sel[t];
        int off_e = 0;
#pragma unroll
        for (int j = 0; j < NEXP; ++j) off_e += (j < e) ? counts[j] : 0;  // no array (rule #20)
        list[off_e + atomicAdd(&cur[e], 1)] = t;
    }
    if (t == 0) {
        int o = 0;
        for (int e = 0; e < NEXP; ++e) { offs[e] = o; o += counts[e]; }
        offs[NEXP] = o;
        int i0 = 0;
        for (int e = 0; e < NEXP; ++e)
            for (int m = 0; m < counts[e]; m += 128) t0[i0++] = (e << 16) | m;
        while (i0 < T0MAX) t0[i0++] = -1;
        int i1 = 0;
        for (int e = 0; e < NEXP; ++e)
            for (int m = 0; m < counts[e]; m += 64) t1[i1++] = (e << 16) | m;
        while (i1 < T1MAX) t1[i1++] = -1;
        laux[0] = 0.f;
    }
}

// ---------------- standalone transpose-convert kernel (small-ws fallback) -------------
template<int K, int NC>
__global__ __launch_bounds__(256) void k_cvt_w(const float* __restrict__ W,
                                               unsigned short* __restrict__ Wt) {
    __shared__ unsigned short T[64 * 68];
    cvt_tile<K, NC>(W, Wt, blockIdx.x, blockIdx.y, T);
}

// ---------------- grouped GEMM: R5 single-buffer structure + compact grid -------------
// 256 thr = 4 waves, per-wave (BM/2)x(BN/2). Single-buffered LDS (best-measured GEMM
// variant: 74us @128x128), XOR swizzle via pre-swizzled global source, global_load_lds
// w=16, compact ttab grid. FUSE adds cvt_w2 blocks (IDs >= NG0) that stream w2 -> W2t
// through the HBM slack while gemm blocks compute; 34.8KB LDS -> 4 gemm blocks/CU
// leaves slots+LDS for cvt backfill throughout.
template<int MODE, int BM_, int BN_, bool FUSE>
__global__ __launch_bounds__(256) void k_gemm(
        const unsigned short* __restrict__ Ain,
        const unsigned short* __restrict__ Wt,
        const float* __restrict__ bias,
        unsigned short* __restrict__ Hout, float* __restrict__ Yout,
        const int* __restrict__ counts, const int* __restrict__ offs,
        const int* __restrict__ list, const int* __restrict__ ttab,
        const float* __restrict__ Wcvt, unsigned short* __restrict__ Wtcvt) {
    static_assert(BM_ % 32 == 0 && BN_ % 32 == 0, "tile");
    constexpr int K    = (MODE == 0) ? DDIM : HDIM;
    constexpr int NC   = (MODE == 0) ? HDIM : DDIM;
    constexpr int NT   = K / BK;
    constexpr int FM   = BM_ / 32;
    constexpr int FN   = BN_ / 32;
    constexpr int LA   = BM_ / 32;   // A loads per thread per tile
    constexpr int LB   = BN_ / 32;
    constexpr int EP   = 136;        // MODE0 epilogue stride (shorts), 16B-mult
    constexpr int STAGE_SH = BM_ * 64 + BN_ * 64;
    constexpr int SH_SZ = (MODE == 0 && BM_ * EP > STAGE_SH) ? BM_ * EP : STAGE_SH;

    __shared__ __align__(16) unsigned short sh[SH_SZ];

    int bx, by;
    if constexpr (FUSE) {
        const int bid = blockIdx.x;
        if (bid >= NG0) {                         // cvt_w2 block
            const int cv = bid - NG0;
            cvt_tile<HDIM, DDIM>(Wcvt, Wtcvt, cv % (DDIM / 64), cv / (DDIM / 64), sh);
            return;
        }
        bx = bid % (NC / BN_); by = bid / (NC / BN_);
    } else {
        bx = blockIdx.x; by = blockIdx.y;
    }

    const int code = ttab[by];
    if (code < 0) return;
    const int e  = code >> 16;
    const int m0 = code & 0xFFFF;
    const int cnt  = counts[e];
    const int base = offs[e];
    const int n0   = bx * BN_;

    unsigned short* Asb = sh;
    unsigned short* Btb = sh + BM_ * 64;

    const int tid  = threadIdx.x;
    const int lane = tid & 63, wid = tid >> 6;
    const int lr = lane >> 3, lc = lane & 7;
    const int sb = (lc * 16) ^ (lr << 4);        // pre-swizzled source byte offset

    const unsigned short* pA[LA];
#pragma unroll
    for (int i = 0; i < LA; ++i) {
        const int r = wid * (BM_ / 4) + i * 8 + lr;
        int rr = m0 + r; if (rr >= cnt) rr = cnt - 1;
        const long grow = (MODE == 0) ? (long)list[base + rr] : (long)(base + rr);
        pA[i] = (const unsigned short*)((const char*)(Ain + grow * K) + sb);
    }
    const unsigned short* We = Wt + (long)e * NC * K;
    const unsigned short* pB[LB];
#pragma unroll
    for (int i = 0; i < LB; ++i) {
        const int r = wid * (BN_ / 4) + i * 8 + lr;
        pB[i] = (const unsigned short*)((const char*)(We + (long)(n0 + r) * K) + sb);
    }

    const int wm = (wid >> 1) * (BM_ / 2);
    const int wn = (wid & 1) * (BN_ / 2);
    const int hk = 16 * (lane >> 4);

    const f32x4 zero4 = {0.f, 0.f, 0.f, 0.f};
    f32x4 acc[FM][FN];
#pragma unroll
    for (int i = 0; i < FM; ++i)
#pragma unroll
        for (int j = 0; j < FN; ++j) acc[i][j] = zero4;

    for (int t = 0; t < NT; ++t) {
        __syncthreads();   // prior-iter readers done
#pragma unroll
        for (int i = 0; i < LA; ++i)
            __builtin_amdgcn_global_load_lds((gas_t*)(pA[i] + t * 64),
                (las_t*)(Asb + (wid * (BM_ / 4) + i * 8) * 64), 16, 0, 0);
#pragma unroll
        for (int i = 0; i < LB; ++i)
            __builtin_amdgcn_global_load_lds((gas_t*)(pB[i] + t * 64),
                (las_t*)(Btb + (wid * (BN_ / 4) + i * 8) * 64), 16, 0, 0);
        __syncthreads();   // staging complete
#pragma unroll
        for (int kk = 0; kk < BK; kk += 32) {
            bf16x8 a[FM], b[FN];
#pragma unroll
            for (int mf = 0; mf < FM; ++mf) {
                const int r  = wm + mf * 16 + (lane & 15);
                const int kb = (2 * kk + hk) ^ ((r & 7) << 4);
                a[mf] = *(const bf16x8*)((const char*)Asb + r * 128 + kb);
            }
#pragma unroll
            for (int nf = 0; nf < FN; ++nf) {
                const int cc = wn + nf * 16 + (lane & 15);
                const int kb = (2 * kk + hk) ^ ((cc & 7) << 4);
                b[nf] = *(const bf16x8*)((const char*)Btb + cc * 128 + kb);
            }
            __builtin_amdgcn_s_setprio(1);
#pragma unroll
            for (int mf = 0; mf < FM; ++mf)
#pragma unroll
                for (int nf = 0; nf < FN; ++nf)
                    acc[mf][nf] = __builtin_amdgcn_mfma_f32_16x16x32_bf16(
                        a[mf], b[nf], acc[mf][nf], 0, 0, 0);
            __builtin_amdgcn_s_setprio(0);
        }
    }

    // ---- epilogue ----
    if constexpr (MODE == 0) {
        // bias+gelu -> bf16 tile in LDS ([BM][EP=136] shorts, 272B rows, 16B-aligned),
        // then 16B coalesced stores: thread -> (row = tid>>1, 64-col half).
        __syncthreads();   // all MFMA reads of sh done
#pragma unroll
        for (int nf = 0; nf < FN; ++nf) {
            const int cl = wn + nf * 16 + (lane & 15);
            const float bv = bias[(long)e * NC + n0 + cl];
#pragma unroll
            for (int mf = 0; mf < FM; ++mf) {
#pragma unroll
                for (int ri = 0; ri < 4; ++ri) {
                    const int rl = wm + mf * 16 + (lane >> 4) * 4 + ri;
                    sh[rl * EP + cl] = f2bf(gelu_f(acc[mf][nf][ri] + bv));
                }
            }
        }
        __syncthreads();
        const int row = tid >> 1, ch = (tid & 1) * 64;
        if (m0 + row < cnt) {
            char* dst = (char*)(Hout + (long)(base + m0 + row) * HDIM + n0 + ch);
            const char* srcp = (const char*)sh + row * (EP * 2) + ch * 2;
#pragma unroll
            for (int j = 0; j < 4; ++j) {
                const int4 v0 = *(const int4*)(srcp + j * 32);
                const int4 v1 = *(const int4*)(srcp + j * 32 + 16);
                *(int4*)(dst + j * 32)      = v0;
                *(int4*)(dst + j * 32 + 16) = v1;
            }
        }
    } else {
#pragma unroll
        for (int nf = 0; nf < FN; ++nf) {
            const int coln = n0 + wn + nf * 16 + (lane & 15);
            const float bv = bias[(long)e * NC + coln];
#pragma unroll
            for (int mf = 0; mf < FM; ++mf) {
                const int rb = m0 + wm + mf * 16 + (lane >> 4) * 4;
#pragma unroll
                for (int ri = 0; ri < 4; ++ri) {
                    const int row = rb + ri;
                    if (row < cnt)
                        Yout[(long)list[base + row] * DDIM + coln] = acc[mf][nf][ri] + bv;
                }
            }
        }
    }
}

extern "C" void kernel_launch(void* const* d_in, const int* in_sizes, int n_in,
                              void* d_out, int out_size, void* d_ws, size_t ws_size,
                              hipStream_t stream) {
    const float* x      = (const float*)d_in[0];
    const float* gate_w = (const float*)d_in[1];
    const float* gate_b = (const float*)d_in[2];
    const float* w1     = (const float*)d_in[3];
    const float* b1     = (const float*)d_in[4];
    const float* w2     = (const float*)d_in[5];
    const float* b2     = (const float*)d_in[6];
    float* out = (float*)d_out;

    // workspace layout
    char* ws = (char*)d_ws;
    int* counts  = (int*)(ws);                 // 8
    int* cur     = (int*)(ws + 128);           // 8
    int* offs    = (int*)(ws + 256);           // 9
    int* t0      = (int*)(ws + 512);           // T0MAX
    int* t1      = (int*)(ws + 768);           // T1MAX
    int* sel     = (int*)(ws + 4096);          // 4096
    int* list    = (int*)(ws + 20480);         // 4096
    unsigned short* xb  = (unsigned short*)(ws + 65536);                      // 8 MB
    unsigned short* Hws = (unsigned short*)(ws + 65536 + 8388608);            // 33.5 MB
    unsigned short* W1t = (unsigned short*)(ws + 65536 + 8388608 + 33554432); // 64 MB
    unsigned short* W2s = W1t + (size_t)NEXP * HDIM * DDIM;                   // 64 MB (big path)
    const size_t WS_SMALL = 65536 + 8388608 + 33554432 + 67108864;
    const size_t WS_BIG   = WS_SMALL + 67108864;
    if (ws_size < WS_SMALL) return;  // deterministic fail, no corruption
    const bool big = ws_size >= WS_BIG;
    unsigned short* W2t = big ? W2s : W1t;     // small path reuses W1t region sequentially

    hipMemsetAsync(ws, 0, 256, stream);   // counts + cur

    // gate (+ xb) fused with cvt(w1) -> W1t: independent, both BW-bound
    k_gatecvt<<<NGATE + NCVT1, 256, 0, stream>>>(x, gate_w, gate_b, xb, sel, counts,
                                                 w1, W1t);
    k_fill<<<(NTOK + 255) / 256, 256, 0, stream>>>(sel, counts, cur, offs, list, t0, t1,
                                                   out + (long)NTOK * DDIM);

    if (big) {
        // FFN up+gelu FUSED with cvt(w2)->W2t: gemm blocks 0..NG0-1, cvt blocks behind
        k_gemm<0, 128, 128, true><<<NG0 + NCVT2, 256, 0, stream>>>(
            xb, W1t, b1, Hws, nullptr, counts, offs, list, t0, w2, W2t);
    } else {
        k_gemm<0, 128, 128, false><<<dim3(HDIM / 128, T0MAX), 256, 0, stream>>>(
            xb, W1t, b1, Hws, nullptr, counts, offs, list, t0, nullptr, nullptr);
        k_cvt_w<HDIM, DDIM><<<dim3(DDIM / 64, NEXP * (HDIM / 64)), 256, 0, stream>>>(w2, W2t);
    }

    // FFN down: 64x128 tiles (best-measured GEMM1), compact grid
    k_gemm<1, 64, 128, false><<<dim3(DDIM / 128, T1MAX), 256, 0, stream>>>(
        Hws, W2t, b2, nullptr, out, counts, offs, list, t1, nullptr, nullptr);
}